// Round 14
// baseline (233.630 us; speedup 1.0000x reference)
//
#include <hip/hip_runtime.h>
#include <hip/hip_bf16.h>

#define D_DIM 256
#define K_CODES 1024
#define HW 1024
#define N_VEC 32768
#define N_ELEM 8388608ull

typedef __attribute__((ext_vector_type(8))) short bf16x8;
typedef __attribute__((ext_vector_type(4))) float f32x4;
typedef __attribute__((ext_vector_type(2))) float f32x2;

static __device__ __forceinline__ unsigned short f2bf(float x) {
    union { __hip_bfloat16 h; unsigned short u; } cvt;
    cvt.h = __float2bfloat16(x);
    return cvt.u;
}

// ---------------------------------------------------------------------------
// Kernel A (fused prep): codebook -> bf16 B-fragment order + codebook norms
// + zero counts/lossacc. 128 blocks x 256.
// ---------------------------------------------------------------------------
__global__ __launch_bounds__(256) void prep_kernel(const float* __restrict__ cb,
                                                   unsigned short* __restrict__ cbb,
                                                   float* __restrict__ cnorm,
                                                   int* __restrict__ counts,
                                                   float* __restrict__ lossacc) {
    int slot = blockIdx.x * 256 + threadIdx.x;  // 0 .. 32767
    {
        int lane = slot & 63;
        int dchunk = (slot >> 6) & 7;
        int ktile = slot >> 9;
        int code = ktile * 16 + (lane & 15);
        int d0 = dchunk * 32 + (lane >> 4) * 8;
        const float4* src = (const float4*)(cb + (size_t)code * D_DIM + d0);
        float4 v0 = src[0], v1 = src[1];
        int4 o;
        o.x = f2bf(v0.x) | ((unsigned)f2bf(v0.y) << 16);
        o.y = f2bf(v0.z) | ((unsigned)f2bf(v0.w) << 16);
        o.z = f2bf(v1.x) | ((unsigned)f2bf(v1.y) << 16);
        o.w = f2bf(v1.z) | ((unsigned)f2bf(v1.w) << 16);
        *(int4*)(cbb + (size_t)slot * 8) = o;
    }
    if (slot < 8192) {
        if (slot < K_CODES) counts[slot] = 0;
        if (slot == K_CODES) lossacc[0] = 0.f;
        int k = slot >> 3;
        int part = slot & 7;
        const float4* row = (const float4*)(cb + (size_t)k * D_DIM + part * 32);
        float s = 0.f;
#pragma unroll
        for (int i = 0; i < 8; i++) {
            float4 v = row[i];
            s = fmaf(v.x, v.x, s);
            s = fmaf(v.y, v.y, s);
            s = fmaf(v.z, v.z, s);
            s = fmaf(v.w, v.w, s);
        }
        s += __shfl_xor(s, 1);
        s += __shfl_xor(s, 2);
        s += __shfl_xor(s, 4);
        if (part == 0) cnorm[k] = s;
    }
}

// ---------------------------------------------------------------------------
// Kernel B (FUSED, WAVE-K-SPECIALIZED): argmin MFMA + STE + loss + enc.
// R12 post-mortem: main loop was LDS-ISSUE-BOUND (~20us): all 8 waves/CU
// read the full 512KB codebook -> 4MB/CU ds_read. R13: wave w reads ONLY its
// ktile (8KB of each 32KB chunk) but computes against ALL 4 ntiles of the
// block (A-frags exchanged once through LDS at prologue; Ar[4][8]=128 VGPR).
// Per-CU LDS reads drop 4x (20->5us); MFMA (~8us/CU) becomes the bound.
// Argmin: waves own disjoint k-sets; per-n combine across waves via LDS with
// (d,k)-lex compare = exact global first-min tiebreak.
// Chunks 32KB x 2 buffers (16 chunks, vmcnt(0)+barrier each; 2 blocks/CU
// cover drains). Block geometry (512 x 64n) + entire R12 epilogue unchanged.
// cbb aliases enc rows 0..128: blocks 0..2 skip enc; finalize writes 0..191.
// ---------------------------------------------------------------------------
__global__ __launch_bounds__(256, 2) void fused_vq(const float* __restrict__ z,
                                                   const unsigned short* __restrict__ cbb,
                                                   const float* __restrict__ cnorm,
                                                   const float* __restrict__ cb,
                                                   int* __restrict__ indices,
                                                   int* __restrict__ counts,
                                                   float* __restrict__ out,
                                                   float* __restrict__ enc,
                                                   float* __restrict__ lossacc) {
    // [Bbuf 2x32KB | cnl 4KB] overlaid by qs[64][257] f32 in the epilogue
    __shared__ __align__(16) char smem[69632];
    unsigned short* Bb0 = (unsigned short*)smem;  // 2 x 16384 ushort
    float* cnl = (float*)(smem + 65536);          // 1024 f32
    float* qs = (float*)smem;                     // [64][257] f32 (epilogue)
    __shared__ float candd[4][64];
    __shared__ int candk[4][64];
    __shared__ int bk[64];
    __shared__ float wsum[4];
    const int t = threadIdx.x;
    const int lane = t & 63;
    const int w = t >> 6;        // wave 0..3 = k-specialist w
    const int row = lane & 15;
    const int dq = (lane >> 4) * 8;
    const int col = lane & 15;
    const int n = blockIdx.x * 64 + w * 16 + row;  // wave's OWN ntile row (load only)
    const int b = n >> 10;
    const int hw = n & (HW - 1);

    // ---- cnorm -> LDS ----
    {
        float4 cv = ((const float4*)cnorm)[t];
        ((float4*)cnl)[t] = cv;
    }
    asm volatile("s_waitcnt lgkmcnt(0)" ::: "memory");

    auto stage = [&](int c) {  // chunk c = global ktiles 4c..4c+3 = 32KB
        const unsigned int* gsrc = (const unsigned int*)(cbb + (size_t)c * 16384);
        unsigned int* l = (unsigned int*)(Bb0 + (size_t)(c & 1) * 16384);
#pragma unroll
        for (int p = 0; p < 8; p++) {
            int off = (p * 256 + t) * 4;
            __builtin_amdgcn_global_load_lds(
                (const __attribute__((address_space(1))) unsigned int*)(gsrc + off),
                (__attribute__((address_space(3))) unsigned int*)(l + off), 16, 0, 0);
        }
    };

    // ---- early DMA: chunk 0 staged into buf0 during the whole prologue ----
    stage(0);

    // ---- prologue: load OWN ntile z -> bf16 frags -> A_lds (= buf1) ----
    unsigned short* Al = Bb0 + 16384;  // buf1 doubles as A-exchange scratch
#pragma unroll
    for (int dc = 0; dc < 8; dc++) {
        const float* src = z + (((size_t)(b * D_DIM + dc * 32 + dq)) << 10) + hw;
        union { bf16x8 v; unsigned short u[8]; } pk;
#pragma unroll
        for (int j = 0; j < 8; j++) pk.u[j] = f2bf(src[(size_t)j << 10]);
        *(bf16x8*)&Al[((w * 8 + dc) * 64 + lane) * 8] = pk.v;
    }
    asm volatile("s_waitcnt lgkmcnt(0)" ::: "memory");
    __builtin_amdgcn_s_barrier();  // A_lds complete (all 4 ntiles)
    __builtin_amdgcn_sched_barrier(0);

    // ---- read ALL 4 ntiles' A fragments (128 VGPR) ----
    bf16x8 Ar[4][8];
#pragma unroll
    for (int nt = 0; nt < 4; nt++)
#pragma unroll
        for (int dc = 0; dc < 8; dc++)
            Ar[nt][dc] = *(const bf16x8*)&Al[((nt * 8 + dc) * 64 + lane) * 8];
    asm volatile("s_waitcnt lgkmcnt(0)" ::: "memory");  // Ar in regs before
    __builtin_amdgcn_sched_barrier(0);                  // loop barrier frees buf1

    float bestd[4][4];
    int bestk[4][4];
#pragma unroll
    for (int nt = 0; nt < 4; nt++)
#pragma unroll
        for (int r = 0; r < 4; r++) { bestd[nt][r] = 3.4e38f; bestk[nt][r] = 0; }

    // ---- chunk body: wave w reads ONLY its ktile (8KB), 32 MFMAs ----
    auto chunk_body = [&](int c) {
        const unsigned short* Bb = Bb0 + (size_t)(c & 1) * 16384;
        bf16x8 bb[8];
#pragma unroll
        for (int dc = 0; dc < 8; dc++)
            bb[dc] = *(const bf16x8*)&Bb[((w * 8 + dc) * 64 + lane) * 8];
        f32x4 acc[4];
#pragma unroll
        for (int nt = 0; nt < 4; nt++) acc[nt] = (f32x4){0.f, 0.f, 0.f, 0.f};
#pragma unroll
        for (int dc = 0; dc < 8; dc++)
#pragma unroll
            for (int nt = 0; nt < 4; nt++)
                acc[nt] = __builtin_amdgcn_mfma_f32_16x16x32_bf16(
                    Ar[nt][dc], bb[dc], acc[nt], 0, 0, 0);
        const int k = (c * 4 + w) * 16 + col;  // wave's ktile of this chunk
        const float cn = cnl[k];
#pragma unroll
        for (int nt = 0; nt < 4; nt++)
#pragma unroll
            for (int r = 0; r < 4; r++) {
                float sc = fmaf(-2.0f, acc[nt][r], cn);
                if (sc < bestd[nt][r]) { bestd[nt][r] = sc; bestk[nt][r] = k; }
            }
    };

    // ---- main loop: 16 chunks, double-buffered ----
    for (int c = 0; c < 15; ++c) {
        asm volatile("s_waitcnt vmcnt(0)" ::: "memory");  // stage(c) landed
        __builtin_amdgcn_s_barrier();
        __builtin_amdgcn_sched_barrier(0);
        stage(c + 1);
        chunk_body(c);
    }
    asm volatile("s_waitcnt vmcnt(0)" ::: "memory");
    __builtin_amdgcn_s_barrier();
    __builtin_amdgcn_sched_barrier(0);
    chunk_body(15);

    // ---- within-wave column reduce (16 cols), stash per-wave candidates ----
#pragma unroll
    for (int nt = 0; nt < 4; nt++)
#pragma unroll
        for (int r = 0; r < 4; r++) {
            float dd = bestd[nt][r];
            int kk = bestk[nt][r];
#pragma unroll
            for (int off = 8; off >= 1; off >>= 1) {
                float d2 = __shfl_xor(dd, off);
                int k2 = __shfl_xor(kk, off);
                if (d2 < dd || (d2 == dd && k2 < kk)) { dd = d2; kk = k2; }
            }
            if ((lane & 15) == 0) {
                int nloc = nt * 16 + (lane >> 4) * 4 + r;  // block-local n
                candd[w][nloc] = dd;
                candk[w][nloc] = kk;
            }
        }
    __syncthreads();

    // ---- cross-wave combine: disjoint k-sets, (d,k)-lex = global first-min ----
    if (t < 64) {
        float dd = candd[0][t];
        int kk = candk[0][t];
#pragma unroll
        for (int ww = 1; ww < 4; ww++) {
            float d2 = candd[ww][t];
            int k2 = candk[ww][t];
            if (d2 < dd || (d2 == dd && k2 < kk)) { dd = d2; kk = k2; }
        }
        bk[t] = kk;
        indices[blockIdx.x * 64 + t] = kk;
        atomicAdd(&counts[kk], 1);
    }
    __syncthreads();  // bk ready; all Bbuf/cnl reads done -> qs may overwrite

    // ---- epilogue 1a: stage 64 winning codebook rows into LDS (qs) ----
    {
        const int j = t >> 2;    // row 0..63
        const int part = t & 3;  // 4 threads per row
        const float4* src = (const float4*)(cb + (size_t)bk[j] * D_DIM);
        float* dst = qs + (size_t)j * 257;
#pragma unroll
        for (int i = 0; i < 16; i++) {
            int f4 = part + 4 * i;  // 0..63
            float4 v = src[f4];
            dst[f4 * 4 + 0] = v.x;
            dst[f4 * 4 + 1] = v.y;
            dst[f4 * 4 + 2] = v.z;
            dst[f4 * 4 + 3] = v.w;
        }
    }
    __syncthreads();

    // ---- epilogue 1b: coalesced quantize + STE + loss ----
    const int hw0 = (blockIdx.x * 64) & (HW - 1);
    const int bb2 = (blockIdx.x * 64) >> 10;
    float ls = 0.f;
#pragma unroll 8
    for (int i = 0; i < 64; i++) {
        int d = w * 64 + i;
        size_t o = (((size_t)(bb2 * D_DIM + d)) << 10) + hw0 + lane;
        float q = qs[(size_t)lane * 257 + d];
        float zv = z[o];
        float e = q - zv;
        out[o] = zv + e;
        ls = fmaf(e, e, ls);
    }

    // ---- epilogue 2: one-hot enc rows, plain stores through L2 ----
    const int n0 = blockIdx.x * 64;
    if (n0 >= 192) {
#pragma unroll 4
        for (int j = 0; j < 64; j++) {
            int idx = bk[j];
            float* rowp = enc + (size_t)(n0 + j) * 1024;
            if (t < 255) {
                int k0 = 2 + t * 4;
                f32x4 v;
                v.x = (k0 == idx) ? 1.f : 0.f;
                v.y = (k0 + 1 == idx) ? 1.f : 0.f;
                v.z = (k0 + 2 == idx) ? 1.f : 0.f;
                v.w = (k0 + 3 == idx) ? 1.f : 0.f;
                *(f32x4*)(rowp + k0) = v;
            } else {
                f32x2 hd, tl;
                hd.x = (0 == idx) ? 1.f : 0.f;
                hd.y = (1 == idx) ? 1.f : 0.f;
                tl.x = (1022 == idx) ? 1.f : 0.f;
                tl.y = (1023 == idx) ? 1.f : 0.f;
                *(f32x2*)rowp = hd;
                *(f32x2*)(rowp + 1022) = tl;
            }
        }
    }

    // ---- loss reduction ----
#pragma unroll
    for (int off = 32; off >= 1; off >>= 1) ls += __shfl_down(ls, off);
    if (lane == 0) wsum[w] = ls;
    __syncthreads();
    if (t == 0) atomicAdd(lossacc, wsum[0] + wsum[1] + wsum[2] + wsum[3]);
}

// ---------------------------------------------------------------------------
// Kernel E: finalize loss + perplexity; writes the 192 deferred enc rows
// (plain stores). 192 blocks.
// ---------------------------------------------------------------------------
__global__ __launch_bounds__(256) void finalize_kernel(const int* __restrict__ counts,
                                                       const float* __restrict__ lossacc,
                                                       const int* __restrict__ indices,
                                                       float* __restrict__ enc,
                                                       float* __restrict__ out_scalars) {
    const int t = threadIdx.x;
    {
        int nrow = blockIdx.x;  // 0..191
        int idx = indices[nrow];
        float* rowp = enc + (size_t)nrow * 1024;
        if (t < 255) {
            int k0 = 2 + t * 4;
            f32x4 v;
            v.x = (k0 == idx) ? 1.f : 0.f;
            v.y = (k0 + 1 == idx) ? 1.f : 0.f;
            v.z = (k0 + 2 == idx) ? 1.f : 0.f;
            v.w = (k0 + 3 == idx) ? 1.f : 0.f;
            *(f32x4*)(rowp + k0) = v;
        } else {
            f32x2 hd, tl;
            hd.x = (0 == idx) ? 1.f : 0.f;
            hd.y = (1 == idx) ? 1.f : 0.f;
            tl.x = (1022 == idx) ? 1.f : 0.f;
            tl.y = (1023 == idx) ? 1.f : 0.f;
            *(f32x2*)rowp = hd;
            *(f32x2*)(rowp + 1022) = tl;
        }
    }
    if (blockIdx.x != 0) return;
    float s = 0.f;
#pragma unroll
    for (int i = 0; i < 4; i++) {
        int k = t + i * 256;
        float p = (float)counts[k] * (1.0f / 32768.0f);
        s += p * logf(p + 1e-10f);
    }
#pragma unroll
    for (int off = 32; off >= 1; off >>= 1) s += __shfl_down(s, off);
    __shared__ float red[4];
    if ((t & 63) == 0) red[t >> 6] = s;
    __syncthreads();
    if (t == 0) {
        float tot = red[0] + red[1] + red[2] + red[3];
        out_scalars[0] = 1.25f * (lossacc[0] * (1.0f / 8388608.0f));
        out_scalars[1] = expf(-tot);
    }
}

// ---------------------------------------------------------------------------
extern "C" void kernel_launch(void* const* d_in, const int* in_sizes, int n_in,
                              void* d_out, int out_size, void* d_ws, size_t ws_size,
                              hipStream_t stream) {
    const float* z = (const float*)d_in[0];
    const float* cb = (const float*)d_in[1];
    float* out = (float*)d_out;
    char* wsb = (char*)d_ws;

    float* cnorm = (float*)wsb;
    int* counts = (int*)(wsb + 4096);
    float* lossacc = (float*)(wsb + 8192);
    int* indices = (int*)(wsb + 16384);

    float* quant = out;
    float* scal = out + N_ELEM;
    float* enc = out + N_ELEM + 2;
    unsigned short* cbb = (unsigned short*)(out + 8388612);

    hipLaunchKernelGGL(prep_kernel, dim3(128), dim3(256), 0, stream, cb, cbb,
                       cnorm, counts, lossacc);
    hipLaunchKernelGGL(fused_vq, dim3(512), dim3(256), 0, stream, z, cbb,
                       cnorm, cb, indices, counts, quant, enc, lossacc);
    hipLaunchKernelGGL(finalize_kernel, dim3(192), dim3(256), 0, stream, counts,
                       lossacc, indices, enc, scal);
}

// Round 15
// 227.847 us; speedup vs baseline: 1.0254x; 1.0254x over previous
//
#include <hip/hip_runtime.h>
#include <hip/hip_bf16.h>

#define D_DIM 256
#define K_CODES 1024
#define HW 1024
#define N_VEC 32768
#define N_ELEM 8388608ull

typedef __attribute__((ext_vector_type(8))) short bf16x8;
typedef __attribute__((ext_vector_type(4))) float f32x4;
typedef __attribute__((ext_vector_type(2))) float f32x2;

static __device__ __forceinline__ unsigned short f2bf(float x) {
    union { __hip_bfloat16 h; unsigned short u; } cvt;
    cvt.h = __float2bfloat16(x);
    return cvt.u;
}

// ---------------------------------------------------------------------------
// Kernel A (fused prep): codebook -> bf16 B-fragment order + codebook norms
// + zero counts/lossacc. 128 blocks x 256.
// ---------------------------------------------------------------------------
__global__ __launch_bounds__(256) void prep_kernel(const float* __restrict__ cb,
                                                   unsigned short* __restrict__ cbb,
                                                   float* __restrict__ cnorm,
                                                   int* __restrict__ counts,
                                                   float* __restrict__ lossacc) {
    int slot = blockIdx.x * 256 + threadIdx.x;  // 0 .. 32767
    {
        int lane = slot & 63;
        int dchunk = (slot >> 6) & 7;
        int ktile = slot >> 9;
        int code = ktile * 16 + (lane & 15);
        int d0 = dchunk * 32 + (lane >> 4) * 8;
        const float4* src = (const float4*)(cb + (size_t)code * D_DIM + d0);
        float4 v0 = src[0], v1 = src[1];
        int4 o;
        o.x = f2bf(v0.x) | ((unsigned)f2bf(v0.y) << 16);
        o.y = f2bf(v0.z) | ((unsigned)f2bf(v0.w) << 16);
        o.z = f2bf(v1.x) | ((unsigned)f2bf(v1.y) << 16);
        o.w = f2bf(v1.z) | ((unsigned)f2bf(v1.w) << 16);
        *(int4*)(cbb + (size_t)slot * 8) = o;
    }
    if (slot < 8192) {
        if (slot < K_CODES) counts[slot] = 0;
        if (slot == K_CODES) lossacc[0] = 0.f;
        int k = slot >> 3;
        int part = slot & 7;
        const float4* row = (const float4*)(cb + (size_t)k * D_DIM + part * 32);
        float s = 0.f;
#pragma unroll
        for (int i = 0; i < 8; i++) {
            float4 v = row[i];
            s = fmaf(v.x, v.x, s);
            s = fmaf(v.y, v.y, s);
            s = fmaf(v.z, v.z, s);
            s = fmaf(v.w, v.w, s);
        }
        s += __shfl_xor(s, 1);
        s += __shfl_xor(s, 2);
        s += __shfl_xor(s, 4);
        if (part == 0) cnorm[k] = s;
    }
}

// ---------------------------------------------------------------------------
// Kernel B (FUSED, 2-WAY K-SPECIALIZED): argmin MFMA + STE + loss + enc.
// R14 post-mortem: 4-way k-spec regressed (fused 78->108) from (a) Ar[4][8]
// =128 VGPR spilled (VGPR_Count=100), (b) depth-1 vmcnt(0) pipeline (R7's
// proven-latency-bound structure), (c) new LDS bank conflicts. R15 keeps the
// k-spec idea with R12's BYTE-IDENTICAL pipeline: wave w = (pair p=w>>1,
// spec s=w&1) computes ntiles {2p,2p+1} against ktile s of each 16KB chunk.
// LDS B-reads halve (8 vs 16 ds_read_b128/chunk); MFMA/wave unchanged;
// Ar[2][8]=64 VGPR (~160 total, no spill); NO A-exchange: pair waves load
// the same z rows directly (2nd wave = L1/L2 hit). Disjoint interleaved
// k-sets (s=0: even ktiles, s=1: odd) combine via LDS (d,k)-lex = exact
// global first-min. Stage schedule / buffers / vmcnt(8) depth-3 / epilogues
// identical to R12. cbb aliases enc rows 0..128: blocks 0..2 skip enc;
// finalize writes rows 0..191 after (stream order).
// ---------------------------------------------------------------------------
__global__ __launch_bounds__(256, 2) void fused_vq(const float* __restrict__ z,
                                                   const unsigned short* __restrict__ cbb,
                                                   const float* __restrict__ cnorm,
                                                   const float* __restrict__ cb,
                                                   int* __restrict__ indices,
                                                   int* __restrict__ counts,
                                                   float* __restrict__ out,
                                                   float* __restrict__ enc,
                                                   float* __restrict__ lossacc) {
    // [Bbuf 4x16KB | cnl 4KB] overlaid by qs[64][257] f32 in the epilogue
    __shared__ __align__(16) char smem[69632];
    unsigned short* Bb0 = (unsigned short*)smem;  // 4 x 8192 ushort
    float* cnl = (float*)(smem + 65536);          // 1024 f32
    float* qs = (float*)smem;                     // [64][257] f32 (epilogue)
    __shared__ float candd[2][64];
    __shared__ int candk[2][64];
    __shared__ int bk[64];
    __shared__ float wsum[4];
    const int t = threadIdx.x;
    const int lane = t & 63;
    const int w = t >> 6;
    const int p = w >> 1;   // ntile pair 0..1 (ntiles 2p, 2p+1)
    const int s = w & 1;    // k-specialist: ktile s of each chunk
    const int row = lane & 15;
    const int dq = (lane >> 4) * 8;
    const int col = lane & 15;
    const int bb2 = (blockIdx.x * 64) >> 10;       // uniform per block
    const int hw0 = (blockIdx.x * 64) & (HW - 1);  // uniform per block

    // ---- cnorm -> LDS ----
    {
        float4 cv = ((const float4*)cnorm)[t];
        ((float4*)cnl)[t] = cv;
    }
    asm volatile("s_waitcnt lgkmcnt(0)" ::: "memory");

    auto stage = [&](int c) {  // chunk c = global ktiles 2c,2c+1 = 16KB
        const unsigned int* gsrc = (const unsigned int*)cbb + (size_t)c * 4096;
        unsigned int* l = (unsigned int*)(Bb0 + (size_t)(c & 3) * 8192);
#pragma unroll
        for (int q = 0; q < 4; q++) {
            int off = q * 1024 + t * 4;
            __builtin_amdgcn_global_load_lds(
                (const __attribute__((address_space(1))) unsigned int*)(gsrc + off),
                (__attribute__((address_space(3))) unsigned int*)(l + off), 16, 0, 0);
        }
    };

    // ---- early DMA issue: chunks 0..2 in flight during the z prologue ----
    stage(0);
    stage(1);
    stage(2);

    // ---- prologue: load BOTH ntiles of this wave's pair (pair-mate loads
    // the same addresses -> L1/L2 hit). Ar[2][8] = 64 VGPR. ----
    bf16x8 Ar[2][8];
#pragma unroll
    for (int nt = 0; nt < 2; nt++) {
        const int n = blockIdx.x * 64 + (p * 2 + nt) * 16 + row;
        const int hw = n & (HW - 1);
#pragma unroll
        for (int dc = 0; dc < 8; dc++) {
            const float* src = z + (((size_t)(bb2 * D_DIM + dc * 32 + dq)) << 10) + hw;
            union { bf16x8 v; unsigned short u[8]; } pk;
#pragma unroll
            for (int j = 0; j < 8; j++) pk.u[j] = f2bf(src[(size_t)j << 10]);
            Ar[nt][dc] = pk.v;
        }
    }

    float bestd[2][4];
    int bestk[2][4];
#pragma unroll
    for (int nt = 0; nt < 2; nt++)
#pragma unroll
        for (int r = 0; r < 4; r++) { bestd[nt][r] = 3.4e38f; bestk[nt][r] = 0; }

    // ---- chunk body: wave reads ONLY ktile s (8 ds_read_b128), 16 MFMAs ----
    auto chunk_body = [&](int c) {
        const unsigned short* Bb = Bb0 + (size_t)(c & 3) * 8192;
        bf16x8 bbr[8];
#pragma unroll
        for (int dc = 0; dc < 8; dc++)
            bbr[dc] = *(const bf16x8*)&Bb[((s * 8 + dc) * 64 + lane) * 8];
        f32x4 acc[2];
#pragma unroll
        for (int nt = 0; nt < 2; nt++) acc[nt] = (f32x4){0.f, 0.f, 0.f, 0.f};
#pragma unroll
        for (int dc = 0; dc < 8; dc++)
#pragma unroll
            for (int nt = 0; nt < 2; nt++)
                acc[nt] = __builtin_amdgcn_mfma_f32_16x16x32_bf16(
                    Ar[nt][dc], bbr[dc], acc[nt], 0, 0, 0);
        const int k = (c * 2 + s) * 16 + col;  // wave's ktile of this chunk
        const float cn = cnl[k];
#pragma unroll
        for (int nt = 0; nt < 2; nt++)
#pragma unroll
            for (int r = 0; r < 4; r++) {
                float sc = fmaf(-2.0f, acc[nt][r], cn);
                if (sc < bestd[nt][r]) { bestd[nt][r] = sc; bestk[nt][r] = k; }
            }
    };

    // ---- main loop: 32 chunks, depth-3 counted vmcnt (R12 schedule) ----
    for (int c = 0; c < 29; ++c) {
        asm volatile("s_waitcnt vmcnt(8)" ::: "memory");  // chunk c landed
        __builtin_amdgcn_s_barrier();
        __builtin_amdgcn_sched_barrier(0);
        stage(c + 3);
        chunk_body(c);
    }
    asm volatile("s_waitcnt vmcnt(8)" ::: "memory");
    __builtin_amdgcn_s_barrier();
    __builtin_amdgcn_sched_barrier(0);
    chunk_body(29);
    asm volatile("s_waitcnt vmcnt(4)" ::: "memory");
    __builtin_amdgcn_s_barrier();
    __builtin_amdgcn_sched_barrier(0);
    chunk_body(30);
    asm volatile("s_waitcnt vmcnt(0)" ::: "memory");
    __builtin_amdgcn_s_barrier();
    __builtin_amdgcn_sched_barrier(0);
    chunk_body(31);

    // ---- within-wave column reduce (16 cols); stash per-spec candidates ----
#pragma unroll
    for (int nt = 0; nt < 2; nt++)
#pragma unroll
        for (int r = 0; r < 4; r++) {
            float dd = bestd[nt][r];
            int kk = bestk[nt][r];
#pragma unroll
            for (int off = 8; off >= 1; off >>= 1) {
                float d2 = __shfl_xor(dd, off);
                int k2 = __shfl_xor(kk, off);
                if (d2 < dd || (d2 == dd && k2 < kk)) { dd = d2; kk = k2; }
            }
            if ((lane & 15) == 0) {
                int nloc = (p * 2 + nt) * 16 + (lane >> 4) * 4 + r;  // 0..63
                candd[s][nloc] = dd;
                candk[s][nloc] = kk;
            }
        }
    __syncthreads();

    // ---- cross-spec combine: disjoint k-sets, (d,k)-lex = global first-min ----
    if (t < 64) {
        float dd = candd[0][t];
        int kk = candk[0][t];
        float d2 = candd[1][t];
        int k2 = candk[1][t];
        if (d2 < dd || (d2 == dd && k2 < kk)) { dd = d2; kk = k2; }
        bk[t] = kk;
        indices[blockIdx.x * 64 + t] = kk;
        atomicAdd(&counts[kk], 1);
    }
    __syncthreads();  // bk ready; all Bbuf/cnl reads done -> qs may overwrite

    // ---- epilogue 1a: stage 64 winning codebook rows into LDS (qs) ----
    {
        const int j = t >> 2;     // row 0..63
        const int part = t & 3;   // 4 threads per row
        const float4* src = (const float4*)(cb + (size_t)bk[j] * D_DIM);
        float* dst = qs + (size_t)j * 257;
#pragma unroll
        for (int i = 0; i < 16; i++) {
            int f4 = part + 4 * i;  // 0..63
            float4 v = src[f4];
            dst[f4 * 4 + 0] = v.x;
            dst[f4 * 4 + 1] = v.y;
            dst[f4 * 4 + 2] = v.z;
            dst[f4 * 4 + 3] = v.w;
        }
    }
    __syncthreads();

    // ---- epilogue 1b: coalesced quantize + STE + loss ----
    float ls = 0.f;
#pragma unroll 8
    for (int i = 0; i < 64; i++) {
        int d = w * 64 + i;
        size_t o = (((size_t)(bb2 * D_DIM + d)) << 10) + hw0 + lane;
        float q = qs[(size_t)lane * 257 + d];
        float zv = z[o];
        float e = q - zv;
        out[o] = zv + e;
        ls = fmaf(e, e, ls);
    }

    // ---- epilogue 2: one-hot enc rows, plain stores through L2 ----
    const int n0 = blockIdx.x * 64;
    if (n0 >= 192) {
#pragma unroll 4
        for (int j = 0; j < 64; j++) {
            int idx = bk[j];
            float* rowp = enc + (size_t)(n0 + j) * 1024;
            if (t < 255) {
                int k0 = 2 + t * 4;
                f32x4 v;
                v.x = (k0 == idx) ? 1.f : 0.f;
                v.y = (k0 + 1 == idx) ? 1.f : 0.f;
                v.z = (k0 + 2 == idx) ? 1.f : 0.f;
                v.w = (k0 + 3 == idx) ? 1.f : 0.f;
                *(f32x4*)(rowp + k0) = v;
            } else {
                f32x2 hd, tl;
                hd.x = (0 == idx) ? 1.f : 0.f;
                hd.y = (1 == idx) ? 1.f : 0.f;
                tl.x = (1022 == idx) ? 1.f : 0.f;
                tl.y = (1023 == idx) ? 1.f : 0.f;
                *(f32x2*)rowp = hd;
                *(f32x2*)(rowp + 1022) = tl;
            }
        }
    }

    // ---- loss reduction ----
#pragma unroll
    for (int off = 32; off >= 1; off >>= 1) ls += __shfl_down(ls, off);
    if (lane == 0) wsum[w] = ls;
    __syncthreads();
    if (t == 0) atomicAdd(lossacc, wsum[0] + wsum[1] + wsum[2] + wsum[3]);
}

// ---------------------------------------------------------------------------
// Kernel E: finalize loss + perplexity; writes the 192 deferred enc rows
// (plain stores). 192 blocks.
// ---------------------------------------------------------------------------
__global__ __launch_bounds__(256) void finalize_kernel(const int* __restrict__ counts,
                                                       const float* __restrict__ lossacc,
                                                       const int* __restrict__ indices,
                                                       float* __restrict__ enc,
                                                       float* __restrict__ out_scalars) {
    const int t = threadIdx.x;
    {
        int nrow = blockIdx.x;  // 0..191
        int idx = indices[nrow];
        float* rowp = enc + (size_t)nrow * 1024;
        if (t < 255) {
            int k0 = 2 + t * 4;
            f32x4 v;
            v.x = (k0 == idx) ? 1.f : 0.f;
            v.y = (k0 + 1 == idx) ? 1.f : 0.f;
            v.z = (k0 + 2 == idx) ? 1.f : 0.f;
            v.w = (k0 + 3 == idx) ? 1.f : 0.f;
            *(f32x4*)(rowp + k0) = v;
        } else {
            f32x2 hd, tl;
            hd.x = (0 == idx) ? 1.f : 0.f;
            hd.y = (1 == idx) ? 1.f : 0.f;
            tl.x = (1022 == idx) ? 1.f : 0.f;
            tl.y = (1023 == idx) ? 1.f : 0.f;
            *(f32x2*)rowp = hd;
            *(f32x2*)(rowp + 1022) = tl;
        }
    }
    if (blockIdx.x != 0) return;
    float s = 0.f;
#pragma unroll
    for (int i = 0; i < 4; i++) {
        int k = t + i * 256;
        float p = (float)counts[k] * (1.0f / 32768.0f);
        s += p * logf(p + 1e-10f);
    }
#pragma unroll
    for (int off = 32; off >= 1; off >>= 1) s += __shfl_down(s, off);
    __shared__ float red[4];
    if ((t & 63) == 0) red[t >> 6] = s;
    __syncthreads();
    if (t == 0) {
        float tot = red[0] + red[1] + red[2] + red[3];
        out_scalars[0] = 1.25f * (lossacc[0] * (1.0f / 8388608.0f));
        out_scalars[1] = expf(-tot);
    }
}

// ---------------------------------------------------------------------------
extern "C" void kernel_launch(void* const* d_in, const int* in_sizes, int n_in,
                              void* d_out, int out_size, void* d_ws, size_t ws_size,
                              hipStream_t stream) {
    const float* z = (const float*)d_in[0];
    const float* cb = (const float*)d_in[1];
    float* out = (float*)d_out;
    char* wsb = (char*)d_ws;

    float* cnorm = (float*)wsb;
    int* counts = (int*)(wsb + 4096);
    float* lossacc = (float*)(wsb + 8192);
    int* indices = (int*)(wsb + 16384);

    float* quant = out;
    float* scal = out + N_ELEM;
    float* enc = out + N_ELEM + 2;
    unsigned short* cbb = (unsigned short*)(out + 8388612);

    hipLaunchKernelGGL(prep_kernel, dim3(128), dim3(256), 0, stream, cb, cbb,
                       cnorm, counts, lossacc);
    hipLaunchKernelGGL(fused_vq, dim3(512), dim3(256), 0, stream, z, cbb,
                       cnorm, cb, indices, counts, quant, enc, lossacc);
    hipLaunchKernelGGL(finalize_kernel, dim3(192), dim3(256), 0, stream, counts,
                       lossacc, indices, enc, scal);
}